// Round 12
// baseline (8868.010 us; speedup 1.0000x reference)
//
#include <hip/hip_runtime.h>

#define S_LEN 1024
#define BATCH 64
#define HIDDEN 512
#define NBLK 32            // 32 workers = all CUs of ONE XCD; each owns 16 cols of BOTH layers
#define COLS_PER_BLK 16
#define GRID_CAND 512      // candidate blocks for XCD-pinning
#define TRY_CAP (1 << 20)  // bounded escape: never hit when healthy

typedef __attribute__((ext_vector_type(8))) short short8;   // 8 bf16 (4 VGPRs) MFMA frag
typedef __attribute__((ext_vector_type(4))) float f32x4;    // MFMA accumulator
typedef __attribute__((ext_vector_type(4))) unsigned int u32x4;

__device__ __forceinline__ unsigned short f2bf(float x) {
  unsigned u = __builtin_bit_cast(unsigned, x);
  u += 0x7fffu + ((u >> 16) & 1u);          // round-to-nearest-even
  return (unsigned short)(u >> 16);
}
__device__ __forceinline__ float bf2f(unsigned short h) {
  unsigned u = ((unsigned)h) << 16;
  return __builtin_bit_cast(float, u);
}

// h state layout: MFMA-A-fragment packed, [parity][wid2][kc][lane][8] bf16 shorts.
#define HOFF(p, w, kc, l) ((((((p) * 4 + (w)) * 16 + (kc)) * 64 + (l))) * 8)

// ws layout (uint idx): [0,512) CP epoch flags (32 slots x 16 uints, own 64B line);
// [512] ticket.  byte 65536+: 4 packed h buffers (h0_hi,h0_lo,h1_hi,h1_lo), 65536 shorts each.
__global__ void k_init(unsigned* __restrict__ ws, int* __restrict__ hbufs) {
  int i = blockIdx.x * blockDim.x + threadIdx.x;
  if (i < 1024) ws[i] = 0u;
  for (int k = i; k < 131072; k += gridDim.x * blockDim.x) hbufs[k] = 0;
}

// take an XCD-0 worker slot (or -1): only blocks physically on XCD 0 participate,
// so all workers share one L2. Non-workers exit immediately and free their CU.
__device__ __forceinline__ int take_slot(unsigned* ticket, int* slot_sh) {
  if (threadIdx.x == 0) {
    unsigned xcc;
    asm volatile("s_getreg_b32 %0, hwreg(HW_REG_XCC_ID)" : "=s"(xcc));
    int s = -1;
    if (xcc == 0)
      s = (int)__hip_atomic_fetch_add(ticket, 1u, __ATOMIC_RELAXED,
                                      __HIP_MEMORY_SCOPE_AGENT);
    *slot_sh = s;
  }
  __syncthreads();
  return *slot_sh;
}

__launch_bounds__(512, 1)
__global__ void k_rnn(const int* __restrict__ x, const float* __restrict__ emb,
                      const float* __restrict__ Wih0, const float* __restrict__ b0,
                      const float* __restrict__ Whh0, const float* __restrict__ Wih1,
                      const float* __restrict__ b1, const float* __restrict__ Whh1,
                      float* __restrict__ out, unsigned* __restrict__ ws_u,
                      short* __restrict__ hbase) {
  __shared__ short wlds[8 * 16 * 64 * 8];                 // 128 KB weight fragments
  __shared__ __align__(16) short stage0[2][4][32][8];     // 4 KB (h0 publish)
  __shared__ __align__(16) short stage1[2][4][32][8];     // 4 KB (h1 publish)
  __shared__ float accx[4][8][65];                        // 8.3 KB k-half partials (+pad)
  __shared__ int slot_sh;

  unsigned* flags = ws_u;                   // CP atomic epoch flags (~1.3us barrier, R9)

  const int slot = take_slot(ws_u + 512, &slot_sh);
  if ((unsigned)slot >= NBLK) return;       // not an XCD-0 worker

  const int tid  = threadIdx.x;
  const int wid8 = tid >> 6;                // 0..7
  const int wid2 = wid8 & 3;                // batch band (rows wid2*16..+15)
  const int half = wid8 >> 2;               // k-half: kc in [half*8, half*8+8)
  const int lane = tid & 63;
  const int col0 = slot * COLS_PER_BLK;

  // ---- stage W column-slices into LDS as pre-packed MFMA B-fragments (hi/lo bf16) ----
  {
    const float* Wm[4] = {Wih0, Whh0, Wih1, Whh1};
    const int c = col0 + (lane & 15);
    #pragma unroll
    for (int m = 0; m < 4; ++m) {
      const float* W = Wm[m];
      for (int kc = wid8; kc < 16; kc += 8) {
        const int k0 = kc * 32 + (lane >> 4) * 8;
        const int basei = (kc * 64 + lane) * 8;
        #pragma unroll
        for (int j = 0; j < 8; ++j) {
          float v = W[(size_t)(k0 + j) * HIDDEN + c];
          unsigned short vh = f2bf(v);
          wlds[(m * 2    ) * 8192 + basei + j] = (short)vh;
          wlds[(m * 2 + 1) * 8192 + basei + j] = (short)f2bf(v - bf2f(vh));
        }
      }
    }
  }
  __syncthreads();

  short* h0_hi = hbase;                       // packed, 65536 shorts each
  short* h0_lo = hbase + 65536;
  short* h1_hi = hbase + 131072;
  short* h1_lo = hbase + 196608;

  const int arow  = wid2 * 16 + (lane & 15);  // A-fragment row = batch index
  const int kgo   = (lane >> 4) * 8;          // k offset inside a 32-chunk
  const int ccol  = col0 + (lane & 15);       // D col (m89-verified C/D map)
  const int drow0 = wid2 * 16 + (lane >> 4) * 4; // D row base
  const float bc0 = b0[ccol];
  const float bc1 = b1[ccol];

  // publication coords: block's 16 cols live in half of one 32-k-chunk
  const int skc   = col0 >> 5;
  const int sub0  = (slot & 1) * 2;
  const int slotb = (lane >> 4) * 4 + 16 * ((lane & 15) >> 3);  // + j = local slot
  const int sjj   = lane & 7;

  float* out_seq = out;                                  // [64][1024][512]
  float* hidden  = out + (size_t)BATCH * S_LEN * HIDDEN; // [2][64][512]

  unsigned*       myflag = flags + slot * 16;            // own 64B line
  const unsigned* pollp  = flags + (lane & 31) * 16;     // wave0: lane l watches slot l&31

  // each wave prefetches ONLY its own k-half of the emb fragments
  short8 ea_reg[8];
  #define LOAD_EA(t) do {                                                   \
    const int xr_ = x[arow * S_LEN + (t)];                                  \
    const float* erow_ = emb + (size_t)xr_ * HIDDEN;                        \
    _Pragma("unroll")                                                       \
    for (int k = 0; k < 8; ++k) {                                           \
      const int kc_ = half * 8 + k;                                         \
      const float4* ep_ = (const float4*)(erow_ + kc_ * 32 + kgo);          \
      float4 e0_ = ep_[0], e1_ = ep_[1];                                    \
      short8 ea_;                                                           \
      ea_[0] = (short)f2bf(e0_.x); ea_[1] = (short)f2bf(e0_.y);             \
      ea_[2] = (short)f2bf(e0_.z); ea_[3] = (short)f2bf(e0_.w);             \
      ea_[4] = (short)f2bf(e1_.x); ea_[5] = (short)f2bf(e1_.y);             \
      ea_[6] = (short)f2bf(e1_.z); ea_[7] = (short)f2bf(e1_.w);             \
      ea_reg[k] = ea_;                                                      \
    } } while (0)

  LOAD_EA(0);

  for (int i = 0; i <= S_LEN; ++i) {
    const int p = i & 1;
    const int q = p ^ 1;
    const bool doL0 = (i < S_LEN);
    const bool doL1 = (i >= 1);

    // ---- BATCH-ISSUE all 32 h-fragment loads before any MFMA ----
    // Independent plain loads (shared XCD-0 L2); static-indexed register arrays
    // (rule #20) -> 32 back-to-back global_load_dwordx4, counted vmcnt at use.
    // Unconditional: at boundary steps the unused buffers hold valid zeros.
    short8 f0h[8], f0l[8], f1h[8], f1l[8];
    #pragma unroll
    for (int k = 0; k < 8; ++k) {
      const int kc = half * 8 + k;
      const int o0 = HOFF(q, wid2, kc, lane);            // h0_{i-1}
      const int o1 = HOFF(p, wid2, kc, lane);            // h1_{i-2}
      f0h[k] = *(const short8*)(h0_hi + o0);
      f0l[k] = *(const short8*)(h0_lo + o0);
      f1h[k] = *(const short8*)(h1_hi + o1);
      f1l[k] = *(const short8*)(h1_lo + o1);
    }

    f32x4 aA0 = {0.f, 0.f, 0.f, 0.f};
    f32x4 aA1 = {0.f, 0.f, 0.f, 0.f};
    f32x4 aB0 = {0.f, 0.f, 0.f, 0.f};
    f32x4 aB1 = {0.f, 0.f, 0.f, 0.f};
    #pragma unroll
    for (int k = 0; k < 8; ++k) {
      const int kc = half * 8 + k;
      const int fb = (kc * 64 + lane) * 8;
      if (doL0) {
        short8 w0h = *(const short8*)&wlds[0 * 8192 + fb];
        short8 w0l = *(const short8*)&wlds[1 * 8192 + fb];
        short8 g0h = *(const short8*)&wlds[2 * 8192 + fb];
        short8 g0l = *(const short8*)&wlds[3 * 8192 + fb];
        f32x4& ac = (k & 1) ? aA1 : aA0;
        ac = __builtin_amdgcn_mfma_f32_16x16x32_bf16(ea_reg[k], w0h, ac, 0, 0, 0);
        ac = __builtin_amdgcn_mfma_f32_16x16x32_bf16(ea_reg[k], w0l, ac, 0, 0, 0);
        ac = __builtin_amdgcn_mfma_f32_16x16x32_bf16(f0h[k], g0h, ac, 0, 0, 0);
        ac = __builtin_amdgcn_mfma_f32_16x16x32_bf16(f0h[k], g0l, ac, 0, 0, 0);
        ac = __builtin_amdgcn_mfma_f32_16x16x32_bf16(f0l[k], g0h, ac, 0, 0, 0);
      }
      if (doL1) {
        short8 w1h = *(const short8*)&wlds[4 * 8192 + fb];
        short8 w1l = *(const short8*)&wlds[5 * 8192 + fb];
        short8 g1h = *(const short8*)&wlds[6 * 8192 + fb];
        short8 g1l = *(const short8*)&wlds[7 * 8192 + fb];
        f32x4& bcx = (k & 1) ? aB1 : aB0;
        bcx = __builtin_amdgcn_mfma_f32_16x16x32_bf16(f0h[k], w1h, bcx, 0, 0, 0);
        bcx = __builtin_amdgcn_mfma_f32_16x16x32_bf16(f0h[k], w1l, bcx, 0, 0, 0);
        bcx = __builtin_amdgcn_mfma_f32_16x16x32_bf16(f0l[k], w1h, bcx, 0, 0, 0);
        bcx = __builtin_amdgcn_mfma_f32_16x16x32_bf16(f1h[k], g1h, bcx, 0, 0, 0);
        bcx = __builtin_amdgcn_mfma_f32_16x16x32_bf16(f1h[k], g1l, bcx, 0, 0, 0);
        bcx = __builtin_amdgcn_mfma_f32_16x16x32_bf16(f1l[k], g1h, bcx, 0, 0, 0);
      }
    }

    // ---- k-half reduction: half 1 -> LDS; half 0 finalizes ----
    if (half == 1) {
      #pragma unroll
      for (int j = 0; j < 4; ++j) {
        accx[wid2][j    ][lane] = aA0[j] + aA1[j];
        accx[wid2][4 + j][lane] = aB0[j] + aB1[j];
      }
    }
    __syncthreads();

    // half 0: finalize h, publish to shared L2 NOW; hold out/hidden values in
    // registers — their HBM stores are deferred past the arrival flag (they have
    // no ordering requirement vs the barrier and their ACK is ~1us of HBM RTT).
    float hv0[4] = {0.f, 0.f, 0.f, 0.f};
    float hv1[4] = {0.f, 0.f, 0.f, 0.f};
    if (half == 0) {
      if (doL0) {
        #pragma unroll
        for (int j = 0; j < 4; ++j) {
          hv0[j] = tanhf(aA0[j] + aA1[j] + accx[wid2][j][lane] + bc0);
          unsigned short hi = f2bf(hv0[j]);
          unsigned short lo = f2bf(hv0[j] - bf2f(hi));
          stage0[0][wid2][slotb + j][sjj] = (short)hi;
          stage0[1][wid2][slotb + j][sjj] = (short)lo;
        }
      }
      if (doL1) {
        #pragma unroll
        for (int j = 0; j < 4; ++j) {
          hv1[j] = tanhf(aB0[j] + aB1[j] + accx[wid2][4 + j][lane] + bc1);
          unsigned short hi = f2bf(hv1[j]);
          unsigned short lo = f2bf(hv1[j] - bf2f(hi));
          stage1[0][wid2][slotb + j][sjj] = (short)hi;
          stage1[1][wid2][slotb + j][sjj] = (short)lo;
        }
      }
      asm volatile("s_waitcnt lgkmcnt(0)" ::: "memory");
      const int l2 = lane & 31, sel = lane >> 5;
      if (doL0) {
        u32x4 v = *(const u32x4*)&stage0[sel][wid2][l2][0];
        short* dst = (sel ? h0_lo : h0_hi) +
                     (((p * 4 + wid2) * 16 + skc) * 64 + sub0 * 16 + l2) * 8;
        *(u32x4*)dst = v;
      }
      if (doL1) {
        u32x4 v = *(const u32x4*)&stage1[sel][wid2][l2][0];
        short* dst = (sel ? h1_lo : h1_hi) +
                     (((q * 4 + wid2) * 16 + skc) * 64 + sub0 * 16 + l2) * 8;
        *(u32x4*)dst = v;
      }
    }

    // deferred output stores (issued after the arrival flag; overlap the poll)
    #define DEFER_OUT() do {                                                 \
      if (half == 0) {                                                       \
        if (doL0 && i == S_LEN - 1) {                                        \
          _Pragma("unroll")                                                  \
          for (int j = 0; j < 4; ++j)                                        \
            hidden[(drow0 + j) * HIDDEN + ccol] = hv0[j];                    \
        }                                                                    \
        if (doL1) {                                                          \
          const int t_ = i - 1;                                              \
          _Pragma("unroll")                                                  \
          for (int j = 0; j < 4; ++j)                                        \
            out_seq[(size_t)(drow0 + j) * S_LEN * HIDDEN +                   \
                    (size_t)t_ * HIDDEN + ccol] = hv1[j];                    \
          if (i == S_LEN) {                                                  \
            _Pragma("unroll")                                                \
            for (int j = 0; j < 4; ++j)                                      \
              hidden[32768 + (drow0 + j) * HIDDEN + ccol] = hv1[j];          \
          }                                                                  \
        }                                                                    \
      } } while (0)

    // ---- minimal barrier (P2 structure, ~1.3us measured) ----
    if (i < S_LEN) {
      asm volatile("s_waitcnt vmcnt(0)" ::: "memory");  // h publishes ACKed by L2
      __syncthreads();                                  // all 8 waves' publishes drained
      if (tid == 0)
        __hip_atomic_store(myflag, (unsigned)(i + 1),
                           __ATOMIC_RELAXED, __HIP_MEMORY_SCOPE_AGENT);
      DEFER_OUT();                         // HBM out stores fly during the poll
      if (i + 1 < S_LEN) LOAD_EA(i + 1);   // overlap emb prefetch with barrier wait
      __builtin_amdgcn_sched_barrier(0);   // pin deferred stores+prefetch before poll
      if (wid8 == 0) {
        int tries = 0;
        for (;;) {
          unsigned f = __hip_atomic_load(pollp, __ATOMIC_RELAXED,
                                         __HIP_MEMORY_SCOPE_AGENT);
          if (__all((int)(f > (unsigned)i))) break;
          if (++tries > TRY_CAP) break;    // bounded escape; never hit when healthy
        }
      }
      __syncthreads();                                  // release waves 1..7
      // NO buffer_inv: vL1 freshness by capacity eviction (256KB h stream vs 32KB L1)
    } else {
      DEFER_OUT();                         // final iteration: no barrier, store now
    }
    #undef DEFER_OUT
  }
  #undef LOAD_EA
}

extern "C" void kernel_launch(void* const* d_in, const int* in_sizes, int n_in,
                              void* d_out, int out_size, void* d_ws, size_t ws_size,
                              hipStream_t stream) {
  const int*   x    = (const int*)d_in[0];
  // d_in[1] = lengths : unused by the reference
  const float* emb  = (const float*)d_in[2];
  const float* Wih0 = (const float*)d_in[3];
  const float* b0   = (const float*)d_in[4];
  const float* Whh0 = (const float*)d_in[5];
  const float* Wih1 = (const float*)d_in[6];
  const float* b1   = (const float*)d_in[7];
  const float* Whh1 = (const float*)d_in[8];
  float* out = (float*)d_out;

  unsigned* ws_u  = (unsigned*)d_ws;
  short*    hbase = (short*)((char*)d_ws + 65536);

  // re-zero flags/ticket + initial h-state every call (ws not re-poisoned between
  // replays; kernel-boundary cache ops make zeros visible device-wide)
  k_init<<<256, 256, 0, stream>>>(ws_u, (int*)hbase);
  k_rnn<<<GRID_CAND, 512, 0, stream>>>(x, emb, Wih0, b0, Whh0, Wih1, b1, Whh1,
                                       out, ws_u, hbase);
}

// Round 13
// 3601.737 us; speedup vs baseline: 2.4621x; 2.4621x over previous
//
#include <hip/hip_runtime.h>

#define S_LEN 1024
#define BATCH 64
#define HIDDEN 512
#define NGROUP 4           // 4 XCD groups; group g owns batch rows [g*16, g*16+16)
#define NBLK 32            // blocks per group = column split (16 cols each)
#define COLS_PER_BLK 16
#define GRID_CAND 512      // candidates; round-robin dispatch fills 32 workers on each XCD 0-3
#define TRY_CAP (1 << 20)  // bounded escape: never hit when healthy

typedef __attribute__((ext_vector_type(8))) short short8;   // 8 bf16 (4 VGPRs) MFMA frag
typedef __attribute__((ext_vector_type(4))) float f32x4;    // MFMA accumulator
typedef __attribute__((ext_vector_type(4))) unsigned int u32x4;

__device__ __forceinline__ unsigned short f2bf(float x) {
  unsigned u = __builtin_bit_cast(unsigned, x);
  u += 0x7fffu + ((u >> 16) & 1u);          // round-to-nearest-even
  return (unsigned short)(u >> 16);
}
__device__ __forceinline__ float bf2f(unsigned short h) {
  unsigned u = ((unsigned)h) << 16;
  return __builtin_bit_cast(float, u);
}

// h packed per group/buffer: [parity][kc][lane][8] bf16 shorts (16-row A-fragments)
#define HOFF(p, kc, l) ((((p) * 16 + (kc)) * 64 + (l)) * 8)

// ws layout (uint idx): [0,2048) flags (group g at [g*512,g*512+512), slot s at +s*16);
// [2048,2112) per-XCD tickets (xcc*16). byte 16384+: h buffers, group g at g*65536
// shorts: h0_hi +0, h0_lo +16384, h1_hi +32768, h1_lo +49152 (each [2][16][64][8]).
__global__ void k_init(unsigned* __restrict__ ws, int* __restrict__ hbufs) {
  int i = blockIdx.x * blockDim.x + threadIdx.x;
  if (i < 4096) ws[i] = 0u;
  for (int k = i; k < 131072; k += gridDim.x * blockDim.x) hbufs[k] = 0;
}

__launch_bounds__(256, 1)
__global__ void k_rnn(const int* __restrict__ x, const float* __restrict__ emb,
                      const float* __restrict__ Wih0, const float* __restrict__ b0,
                      const float* __restrict__ Whh0, const float* __restrict__ Wih1,
                      const float* __restrict__ b1, const float* __restrict__ Whh1,
                      float* __restrict__ out, unsigned* __restrict__ ws_u,
                      short* __restrict__ hbase) {
  __shared__ short wlds[8 * 16 * 64 * 8];                 // 128 KB weight fragments
  __shared__ __align__(16) short stage0[2][32][8];        // 1 KB (h0 publish)
  __shared__ __align__(16) short stage1[2][32][8];        // 1 KB (h1 publish)
  __shared__ float accx[3][8][68];                        // 6.5 KB k-split partials (+pad)
  __shared__ int slot_sh, grp_sh;

  // ---- per-XCD worker slot: group = XCC_ID (0..3), slot = ticket within group ----
  if (threadIdx.x == 0) {
    unsigned xcc;
    asm volatile("s_getreg_b32 %0, hwreg(HW_REG_XCC_ID)" : "=s"(xcc));
    int s = -1;
    if (xcc < NGROUP)
      s = (int)__hip_atomic_fetch_add(ws_u + 2048 + xcc * 16, 1u,
                                      __ATOMIC_RELAXED, __HIP_MEMORY_SCOPE_AGENT);
    slot_sh = s; grp_sh = (int)xcc;
  }
  __syncthreads();
  const int slot = slot_sh, grp = grp_sh;
  if ((unsigned)slot >= NBLK) return;       // not a worker

  const int tid  = threadIdx.x;
  const int wid  = tid >> 6;                // 0..3; wave covers kc [wid*4, wid*4+4)
  const int lane = tid & 63;
  const int col0 = slot * COLS_PER_BLK;

  // ---- stage W column-slices into LDS as pre-packed MFMA B-fragments (hi/lo bf16) ----
  {
    const float* Wm[4] = {Wih0, Whh0, Wih1, Whh1};
    const int c = col0 + (lane & 15);
    #pragma unroll
    for (int m = 0; m < 4; ++m) {
      const float* W = Wm[m];
      for (int kc = wid; kc < 16; kc += 4) {
        const int k0 = kc * 32 + (lane >> 4) * 8;
        const int basei = (kc * 64 + lane) * 8;
        #pragma unroll
        for (int j = 0; j < 8; ++j) {
          float v = W[(size_t)(k0 + j) * HIDDEN + c];
          unsigned short vh = f2bf(v);
          wlds[(m * 2    ) * 8192 + basei + j] = (short)vh;
          wlds[(m * 2 + 1) * 8192 + basei + j] = (short)f2bf(v - bf2f(vh));
        }
      }
    }
  }
  __syncthreads();

  short* gh    = hbase + grp * 65536;       // this group's 128KB h region
  short* h0_hi = gh;
  short* h0_lo = gh + 16384;
  short* h1_hi = gh + 32768;
  short* h1_lo = gh + 49152;

  const int row0  = grp * 16;                 // group's batch-row base
  const int arow  = row0 + (lane & 15);       // A row (emb gather)
  const int kgo   = (lane >> 4) * 8;          // k offset inside a 32-chunk
  const int ccol  = col0 + (lane & 15);       // D col (m89-verified C/D map)
  const int drow0 = (lane >> 4) * 4;          // local D row base (wave-0 finalize)
  const float bc0 = b0[ccol];
  const float bc1 = b1[ccol];

  // publication coords: block's 16 cols = half of one 32-k-chunk
  const int skc   = col0 >> 5;
  const int sub0  = (slot & 1) * 2;
  const int sel2  = (lane & 15) >> 3;         // which 8-col sub within the 16
  const int sjj   = lane & 7;

  float* out_seq = out;                                  // [64][1024][512]
  float* hidden  = out + (size_t)BATCH * S_LEN * HIDDEN; // [2][64][512]

  unsigned* gflags = ws_u + grp * 512;
  unsigned*       myflag = gflags + slot * 16;           // own 64B line
  const unsigned* pollp  = gflags + (lane & 31) * 16;    // wave0 lane l -> slot l&31

  // each wave prefetches only its 4 kc of the emb fragments
  short8 ea_reg[4];
  #define LOAD_EA(t) do {                                                   \
    const int xr_ = x[arow * S_LEN + (t)];                                  \
    const float* erow_ = emb + (size_t)xr_ * HIDDEN;                        \
    _Pragma("unroll")                                                       \
    for (int k2 = 0; k2 < 4; ++k2) {                                        \
      const float4* ep_ = (const float4*)(erow_ + (wid * 4 + k2) * 32 + kgo); \
      float4 e0_ = ep_[0], e1_ = ep_[1];                                    \
      short8 ea_;                                                           \
      ea_[0] = (short)f2bf(e0_.x); ea_[1] = (short)f2bf(e0_.y);             \
      ea_[2] = (short)f2bf(e0_.z); ea_[3] = (short)f2bf(e0_.w);             \
      ea_[4] = (short)f2bf(e1_.x); ea_[5] = (short)f2bf(e1_.y);             \
      ea_[6] = (short)f2bf(e1_.z); ea_[7] = (short)f2bf(e1_.w);             \
      ea_reg[k2] = ea_;                                                     \
    } } while (0)

  LOAD_EA(0);

  for (int i = 0; i <= S_LEN; ++i) {
    const int p = i & 1;
    const int q = p ^ 1;
    const bool doL0 = (i < S_LEN);
    const bool doL1 = (i >= 1);

    // ---- partial compute: this wave covers 4 of 16 k-chunks (group-local h) ----
    // Plain loads from the group's XCD L2. No buffer_inv: ~72KB/step streams through
    // the 32KB vL1, so any 2-step-old line is evicted before re-read (R11-proven).
    f32x4 aA0 = {0.f, 0.f, 0.f, 0.f};
    f32x4 aA1 = {0.f, 0.f, 0.f, 0.f};
    f32x4 aB0 = {0.f, 0.f, 0.f, 0.f};
    f32x4 aB1 = {0.f, 0.f, 0.f, 0.f};
    #pragma unroll
    for (int k2 = 0; k2 < 4; ++k2) {
      const int kc = wid * 4 + k2;
      const int o0 = HOFF(q, kc, lane);                  // h0_{i-1}
      const int o1 = HOFF(p, kc, lane);                  // h1_{i-2}
      short8 ah = *(const short8*)(h0_hi + o0);
      short8 al = *(const short8*)(h0_lo + o0);
      short8 ch = *(const short8*)(h1_hi + o1);
      short8 cl = *(const short8*)(h1_lo + o1);
      const int fb = (kc * 64 + lane) * 8;
      if (doL0) {
        short8 w0h = *(const short8*)&wlds[0 * 8192 + fb];
        short8 w0l = *(const short8*)&wlds[1 * 8192 + fb];
        short8 g0h = *(const short8*)&wlds[2 * 8192 + fb];
        short8 g0l = *(const short8*)&wlds[3 * 8192 + fb];
        f32x4& ac = (k2 & 1) ? aA1 : aA0;
        ac = __builtin_amdgcn_mfma_f32_16x16x32_bf16(ea_reg[k2], w0h, ac, 0, 0, 0);
        ac = __builtin_amdgcn_mfma_f32_16x16x32_bf16(ea_reg[k2], w0l, ac, 0, 0, 0);
        ac = __builtin_amdgcn_mfma_f32_16x16x32_bf16(ah, g0h, ac, 0, 0, 0);
        ac = __builtin_amdgcn_mfma_f32_16x16x32_bf16(ah, g0l, ac, 0, 0, 0);
        ac = __builtin_amdgcn_mfma_f32_16x16x32_bf16(al, g0h, ac, 0, 0, 0);
      }
      if (doL1) {
        short8 w1h = *(const short8*)&wlds[4 * 8192 + fb];
        short8 w1l = *(const short8*)&wlds[5 * 8192 + fb];
        short8 g1h = *(const short8*)&wlds[6 * 8192 + fb];
        short8 g1l = *(const short8*)&wlds[7 * 8192 + fb];
        f32x4& bcx = (k2 & 1) ? aB1 : aB0;
        bcx = __builtin_amdgcn_mfma_f32_16x16x32_bf16(ah, w1h, bcx, 0, 0, 0);
        bcx = __builtin_amdgcn_mfma_f32_16x16x32_bf16(ah, w1l, bcx, 0, 0, 0);
        bcx = __builtin_amdgcn_mfma_f32_16x16x32_bf16(al, w1h, bcx, 0, 0, 0);
        bcx = __builtin_amdgcn_mfma_f32_16x16x32_bf16(ch, g1h, bcx, 0, 0, 0);
        bcx = __builtin_amdgcn_mfma_f32_16x16x32_bf16(ch, g1l, bcx, 0, 0, 0);
        bcx = __builtin_amdgcn_mfma_f32_16x16x32_bf16(cl, g1h, bcx, 0, 0, 0);
      }
    }

    // ---- k-split reduction: waves 1-3 -> LDS; wave 0 finalizes ----
    if (wid) {
      #pragma unroll
      for (int j = 0; j < 4; ++j) {
        accx[wid - 1][j    ][lane] = aA0[j] + aA1[j];
        accx[wid - 1][4 + j][lane] = aB0[j] + aB1[j];
      }
    }
    __syncthreads();

    if (wid == 0) {
      float hv0[4], hv1[4];
      if (doL0) {
        #pragma unroll
        for (int j = 0; j < 4; ++j) {
          float s = aA0[j] + aA1[j] + accx[0][j][lane] + accx[1][j][lane]
                  + accx[2][j][lane] + bc0;
          hv0[j] = tanhf(s);
          unsigned short hi = f2bf(hv0[j]);
          unsigned short lo = f2bf(hv0[j] - bf2f(hi));
          stage0[0][drow0 + j + 16 * sel2][sjj] = (short)hi;
          stage0[1][drow0 + j + 16 * sel2][sjj] = (short)lo;
        }
      }
      if (doL1) {
        #pragma unroll
        for (int j = 0; j < 4; ++j) {
          float s = aB0[j] + aB1[j] + accx[0][4 + j][lane] + accx[1][4 + j][lane]
                  + accx[2][4 + j][lane] + bc1;
          hv1[j] = tanhf(s);
          unsigned short hi = f2bf(hv1[j]);
          unsigned short lo = f2bf(hv1[j] - bf2f(hi));
          stage1[0][drow0 + j + 16 * sel2][sjj] = (short)hi;
          stage1[1][drow0 + j + 16 * sel2][sjj] = (short)lo;
        }
      }
      asm volatile("s_waitcnt lgkmcnt(0)" ::: "memory");  // stage writes visible in-wave
      const int l2 = lane & 31, sel = lane >> 5;          // 32 slots x {hi,lo}
      if (doL0) {
        u32x4 v = *(const u32x4*)&stage0[sel][l2][0];
        short* dst = (sel ? h0_lo : h0_hi) + HOFF(p, skc, sub0 * 16 + l2);
        *(u32x4*)dst = v;                                 // h0_i -> group L2
      }
      if (doL1) {
        u32x4 v = *(const u32x4*)&stage1[sel][l2][0];
        short* dst = (sel ? h1_lo : h1_hi) + HOFF(q, skc, sub0 * 16 + l2);
        *(u32x4*)dst = v;                                 // h1_{i-1} -> group L2
      }
      // outputs (plain stores complete at L2; writeback to HBM is lazy)
      if (doL1) {
        const int t = i - 1;
        #pragma unroll
        for (int j = 0; j < 4; ++j)
          out_seq[(size_t)(row0 + drow0 + j) * S_LEN * HIDDEN
                  + (size_t)t * HIDDEN + ccol] = hv1[j];
        if (i == S_LEN) {
          #pragma unroll
          for (int j = 0; j < 4; ++j)
            hidden[32768 + (row0 + drow0 + j) * HIDDEN + ccol] = hv1[j]; // hidden[1]
        }
      }
      if (doL0 && i == S_LEN - 1) {
        #pragma unroll
        for (int j = 0; j < 4; ++j)
          hidden[(row0 + drow0 + j) * HIDDEN + ccol] = hv0[j];           // hidden[0]
      }
    }

    // ---- GROUP-LOCAL barrier (32 blocks; P2 structure, ~1.3us measured) ----
    if (i < S_LEN) {
      if (wid == 0) {
        asm volatile("s_waitcnt vmcnt(0)" ::: "memory");  // publish ACKed by L2
        if (lane == 0)
          __hip_atomic_store(myflag, (unsigned)(i + 1),
                             __ATOMIC_RELAXED, __HIP_MEMORY_SCOPE_AGENT);
      }
      if (i + 1 < S_LEN) LOAD_EA(i + 1);   // all waves: prefetch overlaps the wait
      __builtin_amdgcn_sched_barrier(0);   // pin prefetch issue before the poll
      if (wid == 0) {
        int tries = 0;
        for (;;) {
          unsigned f = __hip_atomic_load(pollp, __ATOMIC_RELAXED,
                                         __HIP_MEMORY_SCOPE_AGENT);
          if (__all((int)(f > (unsigned)i))) break;
          if (++tries > TRY_CAP) break;    // bounded escape; never hit when healthy
        }
      }
      __syncthreads();                     // release waves 1..3
      // NO buffer_inv: vL1 freshness by capacity eviction (see compute comment)
    }
  }
  #undef LOAD_EA
}

extern "C" void kernel_launch(void* const* d_in, const int* in_sizes, int n_in,
                              void* d_out, int out_size, void* d_ws, size_t ws_size,
                              hipStream_t stream) {
  const int*   x    = (const int*)d_in[0];
  // d_in[1] = lengths : unused by the reference
  const float* emb  = (const float*)d_in[2];
  const float* Wih0 = (const float*)d_in[3];
  const float* b0   = (const float*)d_in[4];
  const float* Whh0 = (const float*)d_in[5];
  const float* Wih1 = (const float*)d_in[6];
  const float* b1   = (const float*)d_in[7];
  const float* Whh1 = (const float*)d_in[8];
  float* out = (float*)d_out;

  unsigned* ws_u  = (unsigned*)d_ws;
  short*    hbase = (short*)((char*)d_ws + 16384);

  // re-zero flags/tickets + initial h-state every call (ws not re-poisoned between
  // replays; kernel-boundary cache ops make zeros visible device-wide)
  k_init<<<256, 256, 0, stream>>>(ws_u, (int*)hbase);
  k_rnn<<<GRID_CAND, 256, 0, stream>>>(x, emb, Wih0, b0, Whh0, Wih1, b1, Whh1,
                                       out, ws_u, hbase);
}